// Round 1
// 187.803 us; speedup vs baseline: 1.0177x; 1.0177x over previous
//
#include <hip/hip_runtime.h>

#define N_NODES 16384
#define F_IN    128
#define F_HID   256
#define F_OUT   128
#define LN_EPS  1e-5f
#define CAP     128   // ELL slots/row; P(deg>128) ~ 1e-20 for Poisson(32)
#define H0STR   136   // LDS h0 stride (ushorts): 272B/row -> bank shift 4/row, 2-way max
#define H1STR   264   // LDS post-LN stride (ushorts): 528B/row -> bank shift 4/row
#define REPSTR  132   // LDS C2 repack stride (ushorts)

typedef __attribute__((ext_vector_type(8))) short bf16x8;
typedef __attribute__((ext_vector_type(4))) float f32x4;

__device__ __forceinline__ unsigned short bf16rne(float f) {
    unsigned u = __float_as_uint(f);
    unsigned r = (u + 0x7fffu + ((u >> 16) & 1u)) >> 16;   // round-to-nearest-even
    return (unsigned short)r;
}
__device__ __forceinline__ float bf_lo(unsigned v) { return __uint_as_float(v << 16); }
__device__ __forceinline__ float bf_hi(unsigned v) { return __uint_as_float(v & 0xffff0000u); }

// ---------------------------------------------------------------------------
// Prelude (one launch): blockIdx ranges do independent prep work.
//  [0,2048)    : x fp32 -> bf16
//  [2048,2176) : W1 [128k x 256n] -> W1t [256n x 128k] bf16
//  [2176,2304) : W2 [256k x 128n] -> W2t [128n x 256k] bf16
//  [2304,2368) : cur[] = 0
//  2368        : detect int64 vs int32 edge_index (odd u32 words all zero)
__global__ void prelude_kernel(const float* __restrict__ x, unsigned short* __restrict__ xb,
                               const float* __restrict__ W1, unsigned short* __restrict__ W1t,
                               const float* __restrict__ W2, unsigned short* __restrict__ W2t,
                               int* __restrict__ cur, const unsigned* __restrict__ ei,
                               int* __restrict__ mode) {
    int b = blockIdx.x, t = threadIdx.x;
    if (b < 2048) {
        int i = (b * 256 + t) * 4;
        float4 v = *(const float4*)&x[i];
        ushort4 o;
        o.x = bf16rne(v.x); o.y = bf16rne(v.y); o.z = bf16rne(v.z); o.w = bf16rne(v.w);
        *(ushort4*)&xb[i] = o;
    } else if (b < 2176) {
        int id = (b - 2048) * 256 + t;        // [0, 32768)
        int n = id >> 7, k = id & 127;
        W1t[id] = bf16rne(W1[(size_t)k * F_HID + n]);
    } else if (b < 2304) {
        int id = (b - 2176) * 256 + t;        // [0, 32768)
        int n = id >> 8, k = id & 255;
        W2t[id] = bf16rne(W2[(size_t)k * F_OUT + n]);
    } else if (b < 2368) {
        cur[(b - 2304) * 256 + t] = 0;
    } else {
        __shared__ int nz;
        if (t == 0) nz = 0;
        __syncthreads();
        for (int it = 0; it < 4; ++it) {
            int idx = 2 * (t + it * 256) + 1;
            if (ei[idx] != 0u) nz = 1;        // benign race
        }
        __syncthreads();
        if (t == 0) *mode = (nz == 0) ? 1 : 0;  // 1 => int64
    }
}

// ---------------------------------------------------------------------------
// ELL fill: 4 independent edges/thread -> 4 overlapping atomic chains.
// Entry = int2{col, edge_id}; dedupe later replaces .y with weight bits.
__global__ void fill_kernel(const void* __restrict__ ei, const int* __restrict__ mode,
                            int* __restrict__ cur, int2* __restrict__ ed, int E) {
    int base = blockIdx.x * 1024 + threadIdx.x;
    int m = *mode;
#pragma unroll
    for (int u = 0; u < 4; ++u) {
        int e = base + u * 256;
        if (e >= E) continue;
        int r, c;
        if (m) {
            const long long* p = (const long long*)ei;
            r = (int)p[e]; c = (int)p[e + E];
        } else {
            const int* p = (const int*)ei;
            r = p[e]; c = p[e + E];
        }
        if (((unsigned)r | (unsigned)c) >= N_NODES) continue;   // replay-safety guard
        int pos = atomicAdd(&cur[r], 1);
        if (pos < CAP) ed[r * CAP + pos] = make_int2(c, e);
    }
}

// ---------------------------------------------------------------------------
// Fused dedupe + SpMM1 + MLP. 16 rows/block, 4 waves.
// Per wave, 4 rows sequentially:
//  1) stage {col, edge_id} in LDS, 2) last-edge-wins dedupe (col-first compare;
//  dups are ~3%/row so common path is 1 LDS broadcast read/iter), weight gather,
//  write weights back to ed.y (for spmm2) + invdeg, 3) gather-SpMM from xb,
//  16 gathers in flight, 4) bf16 h0 -> LDS (never touches HBM).
// Then the block cooperatively runs the row-local MLP on its 16 rows:
//  C1 = h0 @ W1 (ct tiles split 4/wave) -> bias -> LN (cross-wave stat reduce)
//  -> relu -> C2 = H @ W2 (ct tiles split 2/wave) -> repack -> coalesced store.
// mfma_f32_16x16x32_bf16: C/D col=lane&15 row=quad*4+reg; A[m=lane&15][k=quad*8+j].
__launch_bounds__(256)
__global__ void agg_mlp_kernel(const float* __restrict__ ew, int* __restrict__ cur,
                               int2* __restrict__ ed, float* __restrict__ invdeg,
                               const unsigned* __restrict__ xb,
                               const unsigned short* __restrict__ W1t,
                               const unsigned short* __restrict__ W2t,
                               const float* __restrict__ b1,
                               const float* __restrict__ ln_g, const float* __restrict__ ln_b,
                               unsigned short* __restrict__ h2b) {
    __shared__ int   scol[4][CAP];
    __shared__ int   seid[4][CAP];
    __shared__ float sw[4][CAP];
    __shared__ unsigned short H0[16 * H0STR];   // h0 bf16 tile; reused as C2 repack
    __shared__ unsigned short H1[16 * H1STR];   // relu(LN(C1)) bf16 tile
    __shared__ float red[2][4][16];             // LN partial {s,q}[wave][row]

    int t = threadIdx.x, wave = t >> 6, lane = t & 63;
    int lnid = lane & 15, quad = lane >> 4;
    int Rbase = blockIdx.x * 16;

    // ---- aggregation: wave owns rows Rbase + wave*4 + rr ----
    for (int rr = 0; rr < 4; ++rr) {
        int r = Rbase + wave * 4 + rr;
        int d = cur[r];
        if (d > CAP) d = CAP;
        int2* row = ed + (size_t)r * CAP;
        for (int i = lane; i < d; i += 64) {
            int2 e = row[i];
            scol[wave][i] = e.x;
            seid[wave][i] = e.y;
        }
        __syncthreads();   // also orders per-wave LDS (wave-synchronous safety)

        float wsum = 0.0f;
        for (int i = lane; i < d; i += 64) {
            int myc = scol[wave][i], mye = seid[wave][i];
            bool kill = false;
            for (int j = 0; j < d; ++j) {
                if (scol[wave][j] == myc) {              // broadcast read, conflict-free
                    if (seid[wave][j] > mye) { kill = true; break; }
                }
            }
            float w = kill ? 0.0f : ew[mye];
            sw[wave][i] = w;
            ((int*)&row[i])[1] = __float_as_int(w);      // .y: edge_id -> weight (spmm2)
            wsum += w;
        }
        for (int off = 32; off; off >>= 1) wsum += __shfl_xor(wsum, off, 64);
        float inv = 1.0f / (1.0f + wsum);                // +1 self-loop; >=1 so clip no-op
        if (lane == 0) { invdeg[r] = inv; cur[r] = d; }
        __syncthreads();

        unsigned self = xb[r * 64 + lane];
        float ax = bf_lo(self), ay = bf_hi(self);
        int j = 0;
        for (; j + 16 <= d; j += 16) {
            int c[16]; float w[16]; unsigned v[16];
#pragma unroll
            for (int u = 0; u < 16; ++u) { c[u] = scol[wave][j + u]; w[u] = sw[wave][j + u]; }
#pragma unroll
            for (int u = 0; u < 16; ++u) v[u] = xb[c[u] * 64 + lane];
#pragma unroll
            for (int u = 0; u < 16; ++u) { ax += w[u] * bf_lo(v[u]); ay += w[u] * bf_hi(v[u]); }
        }
        for (; j < d; ++j) {
            int cc = scol[wave][j];
            float w = sw[wave][j];
            unsigned v = xb[cc * 64 + lane];
            ax += w * bf_lo(v); ay += w * bf_hi(v);
        }
        float ox = ax * inv, oy = ay * inv;
        unsigned pack = ((unsigned)bf16rne(oy) << 16) | (unsigned)bf16rne(ox);
        *(unsigned*)&H0[(wave * 4 + rr) * H0STR + lane * 2] = pack;   // 4B aligned
    }
    __syncthreads();   // all 16 h0 rows staged

    // ---- stage A: C1[16x256] = h0 @ W1, K=128; wave handles ct = wave*4 + p ----
    bf16x8 a[4];
#pragma unroll
    for (int ch = 0; ch < 4; ++ch)
        a[ch] = *(const bf16x8*)&H0[lnid * H0STR + ch * 32 + quad * 8];   // 16B aligned
    f32x4 acc[4];
#pragma unroll
    for (int p = 0; p < 4; ++p) {
        int ct = wave * 4 + p;
        f32x4 c = {0.0f, 0.0f, 0.0f, 0.0f};
        const unsigned short* wrow = &W1t[(size_t)(ct * 16 + lnid) * F_IN];
#pragma unroll
        for (int ch = 0; ch < 4; ++ch) {
            bf16x8 b = *(const bf16x8*)&wrow[ch * 32 + quad * 8];
            c = __builtin_amdgcn_mfma_f32_16x16x32_bf16(a[ch], b, c, 0, 0, 0);
        }
        acc[p] = c;
    }
    // bias + LN partial stats (rows in (quad,reg); this wave's 64 cols in (p,lnid))
    float s[4] = {0, 0, 0, 0}, q[4] = {0, 0, 0, 0};
#pragma unroll
    for (int p = 0; p < 4; ++p) {
        float bv = b1[(wave * 4 + p) * 16 + lnid];
#pragma unroll
        for (int r = 0; r < 4; ++r) {
            float v = acc[p][r] + bv;
            acc[p][r] = v;
            s[r] += v; q[r] += v * v;
        }
    }
#pragma unroll
    for (int r = 0; r < 4; ++r)
        for (int off = 1; off < 16; off <<= 1) {
            s[r] += __shfl_xor(s[r], off, 64);
            q[r] += __shfl_xor(q[r], off, 64);
        }
    if (lnid == 0) {
#pragma unroll
        for (int r = 0; r < 4; ++r) {
            red[0][wave][quad * 4 + r] = s[r];
            red[1][wave][quad * 4 + r] = q[r];
        }
    }
    __syncthreads();
    float mean[4], rinv[4];
#pragma unroll
    for (int r = 0; r < 4; ++r) {
        int rowi = quad * 4 + r;
        float S = red[0][0][rowi] + red[0][1][rowi] + red[0][2][rowi] + red[0][3][rowi];
        float Q = red[1][0][rowi] + red[1][1][rowi] + red[1][2][rowi] + red[1][3][rowi];
        mean[r] = S * (1.0f / F_HID);
        float var = Q * (1.0f / F_HID) - mean[r] * mean[r];
        rinv[r] = rsqrtf(var + LN_EPS);
    }
#pragma unroll
    for (int p = 0; p < 4; ++p) {
        int c = (wave * 4 + p) * 16 + lnid;
        float g = ln_g[c], bb = ln_b[c];
#pragma unroll
        for (int r = 0; r < 4; ++r) {
            float v = fmaxf((acc[p][r] - mean[r]) * rinv[r] * g + bb, 0.0f);
            H1[(quad * 4 + r) * H1STR + c] = bf16rne(v);
        }
    }
    __syncthreads();   // H1 complete; H0 now dead for ALL waves -> reusable

    // ---- stage B: C2[16x128] = H1 @ W2, K=256; wave handles ct = wave*2 + p ----
    bf16x8 a2[8];
#pragma unroll
    for (int ch = 0; ch < 8; ++ch)
        a2[ch] = *(const bf16x8*)&H1[lnid * H1STR + ch * 32 + quad * 8];  // 16B aligned
    unsigned short* rep = H0;   // repack area (stride 132 fits in 16*136)
#pragma unroll
    for (int p = 0; p < 2; ++p) {
        int ct = wave * 2 + p;
        f32x4 c = {0.0f, 0.0f, 0.0f, 0.0f};
        const unsigned short* wrow = &W2t[(size_t)(ct * 16 + lnid) * F_HID];
#pragma unroll
        for (int ch = 0; ch < 8; ++ch) {
            bf16x8 b = *(const bf16x8*)&wrow[ch * 32 + quad * 8];
            c = __builtin_amdgcn_mfma_f32_16x16x32_bf16(a2[ch], b, c, 0, 0, 0);
        }
#pragma unroll
        for (int r = 0; r < 4; ++r)
            rep[(quad * 4 + r) * REPSTR + ct * 16 + lnid] = bf16rne(c[r]);
    }
    __syncthreads();   // drain before coalesced readback

    // coalesced store: 16 rows x 128 bf16 (512 ushort4, 2 per thread)
#pragma unroll
    for (int p = 0; p < 2; ++p) {
        int flat = p * 256 + t;             // ushort4 id in [0,512)
        int m = flat >> 5, cg = flat & 31;
        *(ushort4*)&h2b[(size_t)(Rbase + m) * F_OUT + cg * 4] =
            *(const ushort4*)&rep[m * REPSTR + cg * 4];
    }
}

// ---------------------------------------------------------------------------
// Gather SpMM (ELL, deduped weights in ed.y): one wave per row, 16 gathers in
// flight. fp32 accumulate. Epilogue: out = acc*invdeg + bias (fp32).
__global__ void spmm2_kernel(const unsigned* __restrict__ xb, const int* __restrict__ cur,
                             const int2* __restrict__ ed, const float* __restrict__ invdeg,
                             const float* __restrict__ bias, float* __restrict__ outp) {
    int wave = threadIdx.x >> 6, lane = threadIdx.x & 63;
    int r = blockIdx.x * 4 + wave;
    const int4* rowq = (const int4*)(ed + r * CAP);
    int d = cur[r];
    if (d > CAP) d = CAP;
    unsigned self = xb[r * 64 + lane];
    float ax = bf_lo(self), ay = bf_hi(self);
    int j = 0;
    for (; j + 16 <= d; j += 16) {
        int4 q[8]; int c[16]; float w[16]; unsigned v[16];
#pragma unroll
        for (int u = 0; u < 8; ++u) q[u] = rowq[(j >> 1) + u];
#pragma unroll
        for (int u = 0; u < 8; ++u) {
            c[2 * u] = q[u].x;     w[2 * u] = __int_as_float(q[u].y);
            c[2 * u + 1] = q[u].z; w[2 * u + 1] = __int_as_float(q[u].w);
        }
#pragma unroll
        for (int u = 0; u < 16; ++u) v[u] = xb[c[u] * 64 + lane];
#pragma unroll
        for (int u = 0; u < 16; ++u) { ax += w[u] * bf_lo(v[u]); ay += w[u] * bf_hi(v[u]); }
    }
    for (; j + 4 <= d; j += 4) {
        int4 q0 = rowq[j >> 1], q1 = rowq[(j >> 1) + 1];
        unsigned v0 = xb[q0.x * 64 + lane];
        unsigned v1 = xb[q0.z * 64 + lane];
        unsigned v2 = xb[q1.x * 64 + lane];
        unsigned v3 = xb[q1.z * 64 + lane];
        float w0 = __int_as_float(q0.y), w1 = __int_as_float(q0.w);
        float w2 = __int_as_float(q1.y), w3 = __int_as_float(q1.w);
        ax += w0 * bf_lo(v0) + w1 * bf_lo(v1) + w2 * bf_lo(v2) + w3 * bf_lo(v3);
        ay += w0 * bf_hi(v0) + w1 * bf_hi(v1) + w2 * bf_hi(v2) + w3 * bf_hi(v3);
    }
    const int2* row = (const int2*)(ed + r * CAP);
    for (; j < d; ++j) {
        int2 e = row[j];
        float w = __int_as_float(e.y);
        unsigned v = xb[e.x * 64 + lane];
        ax += w * bf_lo(v); ay += w * bf_hi(v);
    }
    float inv = invdeg[r];
    float ox = ax * inv + bias[2 * lane];
    float oy = ay * inv + bias[2 * lane + 1];
    ((float2*)outp)[r * 64 + lane] = make_float2(ox, oy);
}

// ---------------------------------------------------------------------------
extern "C" void kernel_launch(void* const* d_in, const int* in_sizes, int n_in,
                              void* d_out, int out_size, void* d_ws, size_t ws_size,
                              hipStream_t stream) {
    const float* x   = (const float*)d_in[0];
    const void*  ei  = d_in[1];
    const float* ew  = (const float*)d_in[2];
    const float* W1  = (const float*)d_in[3];
    const float* b1  = (const float*)d_in[4];
    const float* W2  = (const float*)d_in[5];
    const float* b2  = (const float*)d_in[6];
    const float* lng = (const float*)d_in[7];
    const float* lnb = (const float*)d_in[8];
    float* out = (float*)d_out;
    int E = in_sizes[2];

    char* w = (char*)d_ws;
    size_t off = 0;
    auto take = [&](size_t bytes) -> char* {
        char* p = w + off;
        off += (bytes + 255) & ~(size_t)255;
        return p;
    };
    int*   cur    = (int*)take((size_t)N_NODES * 4);
    float* invdeg = (float*)take((size_t)N_NODES * 4);
    int2*  ed     = (int2*)take((size_t)N_NODES * CAP * 8);
    unsigned short* xb  = (unsigned short*)take((size_t)N_NODES * F_IN * 2);
    unsigned short* h2b = (unsigned short*)take((size_t)N_NODES * F_OUT * 2);
    unsigned short* W1t = (unsigned short*)take((size_t)F_IN * F_HID * 2);
    unsigned short* W2t = (unsigned short*)take((size_t)F_HID * F_OUT * 2);
    int*   mode   = (int*)take(4);

    prelude_kernel<<<2369, 256, 0, stream>>>(x, xb, W1, W1t, W2, W2t, cur,
                                             (const unsigned*)ei, mode);
    fill_kernel<<<(E + 1023) / 1024, 256, 0, stream>>>(ei, mode, cur, ed, E);
    // h0 = bf16( D^-1 (A+I) x ) stays in LDS; h2b = bf16( relu(LN(h0 W1 + b1)) W2 )
    agg_mlp_kernel<<<N_NODES / 16, 256, 0, stream>>>(ew, cur, ed, invdeg,
                                                     (const unsigned*)xb, W1t, W2t,
                                                     b1, lng, lnb, h2b);
    // out = D^-1 (A+I) h2 + b2   (== (D^-1 (A+I) h) W2 + b2 by linearity)
    spmm2_kernel<<<N_NODES / 4, 256, 0, stream>>>((const unsigned*)h2b, cur, ed, invdeg,
                                                  b2, out);
}